// Round 1
// baseline (353.970 us; speedup 1.0000x reference)
//
#include <hip/hip_runtime.h>
#include <math.h>

#define B_ 4
#define S_ 2048
#define D_ 128
#define EPSF 1e-5f
#define BM 32
#define BN 64

// ws layout (floats): [0, 8192) q_norm_sq, [8192, 16384) k_norm_sq, [16384, 24576) l (softmax denom)

__global__ __launch_bounds__(256) void norms_kernel(const float* __restrict__ q,
                                                    const float* __restrict__ k,
                                                    float* __restrict__ ws) {
    int row = blockIdx.x * 4 + (threadIdx.x >> 6);   // one wave per row
    int lane = threadIdx.x & 63;
    const int NR = B_ * S_;
    const float* src = (row < NR) ? q : k;
    int r = (row < NR) ? row : row - NR;
    const float* p = src + (size_t)r * D_;
    float x0 = p[lane], x1 = p[lane + 64];
    float a = x0 * x0 + x1 * x1;
#pragma unroll
    for (int m = 1; m <= 32; m <<= 1) a += __shfl_xor(a, m, 64);
    if (lane == 0) ws[row] = a;
}

__global__ __launch_bounds__(256) void attn_kernel(
    const float* __restrict__ qg, const float* __restrict__ kg, const float* __restrict__ vg,
    const float* __restrict__ cp, const float* __restrict__ betap, const float* __restrict__ biasp,
    const float* __restrict__ ws, float* __restrict__ lws,
    float* __restrict__ houtg, float* __restrict__ woutg) {

    // LDS strides padded: Qs 132 -> broadcast reads bank (4r+d)%32 distinct; KsT/Ps 68 -> b128-aligned (272B)
    __shared__ float Qs[BM][D_ + 4];
    __shared__ float KsT[D_][BN + 4];   // K chunk transposed: KsT[d][c]
    __shared__ float Vs[BN][D_];
    __shared__ float Ps[BM][BN + 4];
    __shared__ float qn_s[BM];
    __shared__ float kn_s[BN];
    __shared__ float l_row[BM];

    const int tid = threadIdx.x;
    // XCD swizzle: batch b pinned to XCD pair so K/V (2MB/batch) stays in that XCD's 4MB L2
    int xcd = blockIdx.x & 7;
    int b = xcd >> 1;
    int rb = (blockIdx.x >> 3) * 2 + (xcd & 1);   // 0..63
    int s0 = rb * BM;

    const float cc = cp[0];
    const float beta = betap[0];
    const float bias = biasp[0];
    const float beta_pos = fmaxf(beta, 0.f) + log1pf(__expf(-fabsf(beta)));  // softplus
    const float sqrt_c = sqrtf(cc);
    const float inv_sqrt_c = 1.f / sqrt_c;

    const float* qn = ws;
    const float* kn = ws + B_ * S_;
    const size_t bS = (size_t)b * S_;

    // stage Q tile (once)
    {
        int d4 = tid & 31, rr0 = tid >> 5;
#pragma unroll
        for (int it = 0; it < 4; ++it) {
            int rr = it * 8 + rr0;
            float4 v = *(const float4*)(qg + (bS + s0 + rr) * D_ + d4 * 4);
            *(float4*)&Qs[rr][d4 * 4] = v;
        }
    }
    if (tid < BM) { qn_s[tid] = qn[bS + s0 + tid]; l_row[tid] = 0.f; }

    // score-phase mapping: 2 rows x 4 cols per lane
    const int cg = tid & 15, rg = tid >> 4;    // rg 0..15
    const int c0 = cg * 4, r0 = rg * 2;
    // PV-phase mapping: 4 rows x 4 cols per lane over O[32][128]
    const int cgv = tid & 31, rgv = tid >> 5;  // rgv 0..7
    const int c0v = cgv * 4, r0v = rgv * 4;

    float o[4][4];
#pragma unroll
    for (int i = 0; i < 4; ++i)
#pragma unroll
        for (int j = 0; j < 4; ++j) o[i][j] = 0.f;

    for (int t0 = 0; t0 < S_; t0 += BN) {
        __syncthreads();   // previous PV done before overwriting LDS
        // stage K chunk transposed: gather 4-row column segment in registers (coalesced global reads),
        // write float4 along c (conflict-free-ish b128 writes)
        {
            int d = tid & 127, seg = tid >> 7;
#pragma unroll
            for (int it = 0; it < 8; ++it) {
                int cbase = it * 8 + seg * 4;
                float f0 = kg[(bS + t0 + cbase + 0) * D_ + d];
                float f1 = kg[(bS + t0 + cbase + 1) * D_ + d];
                float f2 = kg[(bS + t0 + cbase + 2) * D_ + d];
                float f3 = kg[(bS + t0 + cbase + 3) * D_ + d];
                float4 w = {f0, f1, f2, f3};
                *(float4*)&KsT[d][cbase] = w;
            }
        }
        // stage V chunk (row-major)
        {
            int d4 = tid & 31, rv = tid >> 5;
#pragma unroll
            for (int it = 0; it < 8; ++it) {
                int rr = it * 8 + rv;
                *(float4*)&Vs[rr][d4 * 4] = *(const float4*)(vg + (bS + t0 + rr) * D_ + d4 * 4);
            }
        }
        if (tid < BN) kn_s[tid] = kn[bS + t0 + tid];
        __syncthreads();

        // ---- scores: acc[i][j] = q[r0+i] . k[c0+j] ----
        float acc[2][4];
#pragma unroll
        for (int i = 0; i < 2; ++i)
#pragma unroll
            for (int j = 0; j < 4; ++j) acc[i][j] = 0.f;

#pragma unroll 4
        for (int d = 0; d < D_; ++d) {
            float4 kv = *(const float4*)&KsT[d][c0];
            float q0 = Qs[r0][d];
            float q1 = Qs[r0 + 1][d];
            acc[0][0] = fmaf(q0, kv.x, acc[0][0]);
            acc[0][1] = fmaf(q0, kv.y, acc[0][1]);
            acc[0][2] = fmaf(q0, kv.z, acc[0][2]);
            acc[0][3] = fmaf(q0, kv.w, acc[0][3]);
            acc[1][0] = fmaf(q1, kv.x, acc[1][0]);
            acc[1][1] = fmaf(q1, kv.y, acc[1][1]);
            acc[1][2] = fmaf(q1, kv.z, acc[1][2]);
            acc[1][3] = fmaf(q1, kv.w, acc[1][3]);
        }

        // ---- p = exp(-beta_pos*dist - bias), unnormalized (scores <= 0, no max needed) ----
        float lp[2] = {0.f, 0.f};
#pragma unroll
        for (int i = 0; i < 2; ++i) {
            int r = r0 + i;
            float xn = qn_s[r];
            float one_m_cxn = 1.f - cc * xn;
            float4 pv;
            float* pp = &pv.x;
#pragma unroll
            for (int j = 0; j < 4; ++j) {
                float yn = kn_s[c0 + j];
                float diff = xn - 2.f * acc[i][j] + yn;
                float den = one_m_cxn * (1.f - cc * yn);
                den = fmaxf(den, EPSF);
                float arg = 1.f + 2.f * cc * diff / den;
                arg = fmaxf(arg, 1.f + EPSF);
                float dist = __logf(arg + sqrtf(arg * arg - 1.f)) * inv_sqrt_c;
                float p = __expf(fmaf(-beta_pos, dist, -bias));
                pp[j] = p;
                lp[i] += p;
            }
            *(float4*)&Ps[r][c0] = pv;
            *(float4*)(woutg + (bS + s0 + r) * S_ + t0 + c0) = pv;  // unnormalized; pass 2 scales
        }
        // row-sum reduce across the 16-lane cg group
#pragma unroll
        for (int m = 1; m <= 8; m <<= 1) {
            lp[0] += __shfl_xor(lp[0], m, 64);
            lp[1] += __shfl_xor(lp[1], m, 64);
        }
        if (cg == 0) { l_row[r0] += lp[0]; l_row[r0 + 1] += lp[1]; }
        __syncthreads();

        // ---- PV: O[32][128] += P[32][64] * V[64][128] ----
#pragma unroll 4
        for (int kk = 0; kk < BN; ++kk) {
            float4 vv = *(const float4*)&Vs[kk][c0v];
            float pa0 = Ps[r0v + 0][kk];
            float pa1 = Ps[r0v + 1][kk];
            float pa2 = Ps[r0v + 2][kk];
            float pa3 = Ps[r0v + 3][kk];
            o[0][0] = fmaf(pa0, vv.x, o[0][0]);
            o[0][1] = fmaf(pa0, vv.y, o[0][1]);
            o[0][2] = fmaf(pa0, vv.z, o[0][2]);
            o[0][3] = fmaf(pa0, vv.w, o[0][3]);
            o[1][0] = fmaf(pa1, vv.x, o[1][0]);
            o[1][1] = fmaf(pa1, vv.y, o[1][1]);
            o[1][2] = fmaf(pa1, vv.z, o[1][2]);
            o[1][3] = fmaf(pa1, vv.w, o[1][3]);
            o[2][0] = fmaf(pa2, vv.x, o[2][0]);
            o[2][1] = fmaf(pa2, vv.y, o[2][1]);
            o[2][2] = fmaf(pa2, vv.z, o[2][2]);
            o[2][3] = fmaf(pa2, vv.w, o[2][3]);
            o[3][0] = fmaf(pa3, vv.x, o[3][0]);
            o[3][1] = fmaf(pa3, vv.y, o[3][1]);
            o[3][2] = fmaf(pa3, vv.z, o[3][2]);
            o[3][3] = fmaf(pa3, vv.w, o[3][3]);
        }
    }
    __syncthreads();

    // ---- epilogue: normalize O by 1/l, exp map at origin, write hyperbolic out + l to ws ----
#pragma unroll
    for (int i = 0; i < 4; ++i) {
        int r = r0v + i;
        float l = l_row[r];
        float linv = 1.f / l;
        float x0 = o[i][0] * linv;
        float x1 = o[i][1] * linv;
        float x2 = o[i][2] * linv;
        float x3 = o[i][3] * linv;
        float nsq = x0 * x0 + x1 * x1 + x2 * x2 + x3 * x3;
#pragma unroll
        for (int m = 1; m <= 16; m <<= 1) nsq += __shfl_xor(nsq, m, 64);  // 32-lane row group
        float vn = fmaxf(sqrtf(nsq), EPSF);
        float sc = tanhf(sqrt_c * vn) * inv_sqrt_c / vn;
        float4 outv = {x0 * sc, x1 * sc, x2 * sc, x3 * sc};
        *(float4*)(houtg + (bS + s0 + r) * D_ + c0v) = outv;
        if (cgv == 0) lws[bS + s0 + r] = l;
    }
}

__global__ __launch_bounds__(256) void wnorm_kernel(float* __restrict__ w,
                                                    const float* __restrict__ lws) {
    size_t idx = (size_t)blockIdx.x * 256 + threadIdx.x;  // float4 index
    int row = (int)(idx >> 9);                            // S_/4 = 512 float4 per row
    float linv = 1.f / lws[row];
    float4* p = (float4*)w + idx;
    float4 v = *p;
    v.x *= linv; v.y *= linv; v.z *= linv; v.w *= linv;
    *p = v;
}

extern "C" void kernel_launch(void* const* d_in, const int* in_sizes, int n_in,
                              void* d_out, int out_size, void* d_ws, size_t ws_size,
                              hipStream_t stream) {
    const float* q    = (const float*)d_in[0];
    const float* k    = (const float*)d_in[1];
    const float* v    = (const float*)d_in[2];
    const float* c    = (const float*)d_in[3];
    const float* beta = (const float*)d_in[4];
    const float* ab   = (const float*)d_in[5];

    float* out  = (float*)d_out;
    float* hout = out;                          // (B,S,D)
    float* wout = out + (size_t)B_ * S_ * D_;   // (B,S,S)

    float* ws  = (float*)d_ws;                  // norms + l: 24576 floats
    float* lws = ws + 2 * B_ * S_;

    norms_kernel<<<(2 * B_ * S_) / 4, 256, 0, stream>>>(q, k, ws);
    attn_kernel<<<(B_ * S_) / BM, 256, 0, stream>>>(q, k, v, c, beta, ab, ws, lws, hout, wout);
    wnorm_kernel<<<(B_ * S_ * S_ / 4) / 256, 256, 0, stream>>>(wout, lws);
}

// Round 2
// 166.679 us; speedup vs baseline: 2.1237x; 2.1237x over previous
//
#include <hip/hip_runtime.h>
#include <math.h>

#define B_ 4
#define S_ 2048
#define D_ 128
#define EPSF 1e-5f
#define BN 128
#define PSB 272   // Ps row stride in bytes (136 bf16): 16B-aligned rows, 2-way banks

typedef __attribute__((ext_vector_type(8))) short short8;
typedef __attribute__((ext_vector_type(4))) float f32x4;

static __device__ __forceinline__ unsigned short f2bf(float f) {
    unsigned u = __float_as_uint(f);
    return (unsigned short)((u + 0x7fffu + ((u >> 16) & 1u)) >> 16);
}

// ===================== fast path: pre-pass kernels =====================
// ws bytes: [0,32K) qn fp32, [32K,64K) kn, [64K,96K) lws, [96K..) Qb(2MB) Kb(2MB) Vtb(2MB)

__global__ __launch_bounds__(256) void convqk_kernel(const float* __restrict__ q,
                                                     const float* __restrict__ k,
                                                     float* __restrict__ qn, float* __restrict__ kn,
                                                     unsigned* __restrict__ Qb, unsigned* __restrict__ Kb) {
    int row = blockIdx.x * 4 + (threadIdx.x >> 6);   // one wave per row, 16384 rows
    int lane = threadIdx.x & 63;
    const int NR = B_ * S_;
    bool isQ = row < NR;
    int r = isQ ? row : row - NR;
    float2 v = ((const float2*)(isQ ? q : k))[(size_t)r * 64 + lane];
    unsigned pk = (unsigned)f2bf(v.x) | ((unsigned)f2bf(v.y) << 16);
    float nrm = v.x * v.x + v.y * v.y;
#pragma unroll
    for (int m = 1; m <= 32; m <<= 1) nrm += __shfl_xor(nrm, m, 64);
    if (isQ) {
        Qb[(size_t)r * 64 + lane] = pk;              // plain row-major (read direct from global)
        if (lane == 0) qn[r] = nrm;
    } else {
        int c = lane >> 2;                           // 16B chunk index 0..15
        int cs = c ^ (r & 7);                        // bake LDS bank swizzle into global layout
        Kb[(size_t)r * 64 + cs * 4 + (lane & 3)] = pk;
        if (lane == 0) kn[r] = nrm;
    }
}

__global__ __launch_bounds__(256) void convv_kernel(const float* __restrict__ v, uint4* __restrict__ Vtb) {
    __shared__ unsigned short Vs[128 * 132];         // padded stride 132 -> 2-way banks both phases
    int b = blockIdx.x >> 4;
    int t = blockIdx.x & 15;
    int tid = threadIdx.x;
    const float* src = v + ((size_t)b * S_ + t * 128) * D_;
    int d4 = tid & 31, key0 = tid >> 5;
#pragma unroll
    for (int it = 0; it < 16; ++it) {
        int key = key0 + it * 8;
        float4 f = *(const float4*)(src + (size_t)key * D_ + d4 * 4);
        unsigned short* dst = &Vs[key * 132 + d4 * 4];
        dst[0] = f2bf(f.x); dst[1] = f2bf(f.y); dst[2] = f2bf(f.z); dst[3] = f2bf(f.w);
    }
    __syncthreads();
    uint4* tile = Vtb + (size_t)blockIdx.x * (128 * 16);   // [tile][d=128][16 x 16B chunks]
    int d = tid & 127;
    int cl = tid >> 7;
#pragma unroll
    for (int it = 0; it < 8; ++it) {
        int c = cl + it * 2;                         // key-chunk 0..15
        int kb = c * 8;
        unsigned short e0 = Vs[(kb + 0) * 132 + d], e1 = Vs[(kb + 1) * 132 + d];
        unsigned short e2 = Vs[(kb + 2) * 132 + d], e3 = Vs[(kb + 3) * 132 + d];
        unsigned short e4 = Vs[(kb + 4) * 132 + d], e5 = Vs[(kb + 5) * 132 + d];
        unsigned short e6 = Vs[(kb + 6) * 132 + d], e7 = Vs[(kb + 7) * 132 + d];
        uint4 o;
        o.x = (unsigned)e0 | ((unsigned)e1 << 16);
        o.y = (unsigned)e2 | ((unsigned)e3 << 16);
        o.z = (unsigned)e4 | ((unsigned)e5 << 16);
        o.w = (unsigned)e6 | ((unsigned)e7 << 16);
        tile[d * 16 + (c ^ (d & 7))] = o;            // swizzled in global == swizzled in LDS after copy
    }
}

// ===================== fast path: fused MFMA attention =====================

__global__ __launch_bounds__(512, 2) void hattn_kernel(
    const unsigned short* __restrict__ Qb, const char* __restrict__ Kb, const char* __restrict__ Vtb,
    const float* __restrict__ qn, const float* __restrict__ kn,
    const float* __restrict__ cp, const float* __restrict__ betap, const float* __restrict__ biasp,
    float* __restrict__ lws, float* __restrict__ houtg, float* __restrict__ woutg) {

    __shared__ __align__(1024) char smem[75136];
    char* KsB = smem;                                // 32 KB: 128 key-rows x 256B (swizzled)
    char* VtB = smem + 32768;                        // 32 KB: 128 d-rows x 256B (swizzled)
    char* PsB = smem + 65536;                        // 8704 B: 32 rows x 272B
    float* kn_s  = (float*)(smem + 74240);
    float* qn_s  = (float*)(smem + 74752);
    float* l_row = (float*)(smem + 74880);
    float* nsq_s = (float*)(smem + 75008);

    const int tid = threadIdx.x;
    const int lane = tid & 63, wave = tid >> 6;
    const int wm = wave & 1, wn = wave >> 1;         // wm: 16-row half; wn: 32-col / 32-d slice
    const int lm = lane & 15, quad = lane >> 4;

    int xcd = blockIdx.x & 7;                        // pin batch to XCD pair for K/V L2 locality
    int b = xcd >> 1;
    int rb = (blockIdx.x >> 3) * 2 + (xcd & 1);
    int s0 = rb * 32;
    const size_t bS = (size_t)b * S_;

    const float cc = cp[0], beta = betap[0], bias = biasp[0];
    const float beta_pos = fmaxf(beta, 0.f) + log1pf(__expf(-fabsf(beta)));
    const float sqrt_c = sqrtf(cc);
    const float inv_sqrt_c = 1.f / sqrt_c;

    if (tid < 32) {
        qn_s[tid] = qn[bS + s0 + tid];
        l_row[tid] = 0.f;
        nsq_s[tid] = 0.f;
    }

    // Q A-frags live in registers for the whole kernel (A: m=lane&15, k=quad*8+j)
    short8 aq[4];
    {
        const unsigned short* qrow = Qb + (bS + s0 + wm * 16 + lm) * D_;
#pragma unroll
        for (int ks = 0; ks < 4; ++ks)
            aq[ks] = *(const short8*)(qrow + ks * 32 + quad * 8);
    }

    f32x4 o0 = {0.f, 0.f, 0.f, 0.f}, o1 = {0.f, 0.f, 0.f, 0.f};

    const char* KbBase = Kb + bS * 256;
    const char* VtBase = Vtb + (size_t)b * 16 * 32768;

    for (int t = 0; t < S_ / BN; ++t) {
        int t0 = t * BN;
        __syncthreads();
        // stage K chunk + Vt tile: verbatim linear 32KB copies (pre-swizzled)
        {
            const uint4* ksrc = (const uint4*)(KbBase + (size_t)t0 * 256);
            const uint4* vsrc = (const uint4*)(VtBase + (size_t)t * 32768);
            uint4* kd = (uint4*)KsB;
            uint4* vd = (uint4*)VtB;
#pragma unroll
            for (int i = 0; i < 4; ++i) {
                kd[tid + i * 512] = ksrc[tid + i * 512];
                vd[tid + i * 512] = vsrc[tid + i * 512];
            }
            if (tid < BN) kn_s[tid] = kn[bS + t0 + tid];
        }
        __syncthreads();

        // ---- S = Q K^T (wave tile 16x32: 2 n-tiles, A reused) ----
        f32x4 acc0 = {0.f, 0.f, 0.f, 0.f}, acc1 = {0.f, 0.f, 0.f, 0.f};
#pragma unroll
        for (int ks = 0; ks < 4; ++ks) {
            int n0 = wn * 32 + lm;
            int c = ks * 4 + quad;
            short8 b0 = *(const short8*)(KsB + n0 * 256 + ((c ^ (n0 & 7)) * 16));
            int n1 = n0 + 16;
            short8 b1 = *(const short8*)(KsB + n1 * 256 + ((c ^ (n1 & 7)) * 16));
            acc0 = __builtin_amdgcn_mfma_f32_16x16x32_bf16(aq[ks], b0, acc0, 0, 0, 0);
            acc1 = __builtin_amdgcn_mfma_f32_16x16x32_bf16(aq[ks], b1, acc1, 0, 0, 0);
        }

        // ---- dist -> p = exp(score) (unnormalized; scores <= 0) ----
        float lp[4];
#pragma unroll
        for (int r = 0; r < 4; ++r) {
            int row = wm * 16 + quad * 4 + r;        // C/D layout: row=(lane>>4)*4+reg
            float xn = qn_s[row];
            float fx = 1.f - cc * xn;
            float p0, p1;
#pragma unroll
            for (int nt = 0; nt < 2; ++nt) {
                int col = wn * 32 + nt * 16 + lm;    // C/D layout: col=lane&15
                float dot = (nt == 0) ? acc0[r] : acc1[r];
                float yn = kn_s[col];
                float diff = xn - 2.f * dot + yn;
                float den = fmaxf(fx * (1.f - cc * yn), EPSF);
                float arg = fmaf(2.f * cc * diff, __builtin_amdgcn_rcpf(den), 1.f);
                arg = fmaxf(arg, 1.f + EPSF);
                float dist = __logf(arg + sqrtf(arg * arg - 1.f)) * inv_sqrt_c;
                float p = __expf(fmaf(-beta_pos, dist, -bias));
                woutg[(bS + s0 + row) * S_ + t0 + col] = p;
                *(unsigned short*)(PsB + row * PSB + col * 2) = f2bf(p);
                if (nt == 0) p0 = p; else p1 = p;
            }
            lp[r] = p0 + p1;
        }
#pragma unroll
        for (int r = 0; r < 4; ++r) {
            float s = lp[r];
#pragma unroll
            for (int m = 1; m <= 8; m <<= 1) s += __shfl_xor(s, m, 64);
            if (lm == 0) atomicAdd(&l_row[wm * 16 + quad * 4 + r], s);
        }
        __syncthreads();

        // ---- O += P V (wave tile 16 rows x 32 d; A reused over 2 d-tiles) ----
#pragma unroll
        for (int ks = 0; ks < 4; ++ks) {
            short8 ap = *(const short8*)(PsB + (wm * 16 + lm) * PSB + (ks * 32 + quad * 8) * 2);
            int d0 = wn * 32 + lm;
            int c = ks * 4 + quad;
            short8 v0 = *(const short8*)(VtB + d0 * 256 + ((c ^ (d0 & 7)) * 16));
            int d1 = d0 + 16;
            short8 v1 = *(const short8*)(VtB + d1 * 256 + ((c ^ (d1 & 7)) * 16));
            o0 = __builtin_amdgcn_mfma_f32_16x16x32_bf16(ap, v0, o0, 0, 0, 0);
            o1 = __builtin_amdgcn_mfma_f32_16x16x32_bf16(ap, v1, o1, 0, 0, 0);
        }
    }
    __syncthreads();

    // ---- epilogue: normalize, exp-map, store ----
    float xs0[4], xs1[4];
#pragma unroll
    for (int r = 0; r < 4; ++r) {
        int row = wm * 16 + quad * 4 + r;
        float linv = __builtin_amdgcn_rcpf(l_row[row]);
        float x0 = o0[r] * linv, x1 = o1[r] * linv;
        xs0[r] = x0; xs1[r] = x1;
        float np = x0 * x0 + x1 * x1;
#pragma unroll
        for (int m = 1; m <= 8; m <<= 1) np += __shfl_xor(np, m, 64);
        if (lm == 0) atomicAdd(&nsq_s[row], np);
    }
    if (tid < 32) lws[bS + s0 + tid] = l_row[tid];
    __syncthreads();
#pragma unroll
    for (int r = 0; r < 4; ++r) {
        int row = wm * 16 + quad * 4 + r;
        float vn = fmaxf(sqrtf(nsq_s[row]), EPSF);
        float a = sqrt_c * vn;
        float th = 1.f - 2.f * __builtin_amdgcn_rcpf(__expf(2.f * a) + 1.f);
        float sc = th / a;                            // out = x * tanh(a)/a
        houtg[(bS + s0 + row) * D_ + wn * 32 + lm] = xs0[r] * sc;
        houtg[(bS + s0 + row) * D_ + wn * 32 + 16 + lm] = xs1[r] * sc;
    }
}

__global__ __launch_bounds__(256) void wnorm_kernel(float* __restrict__ w,
                                                    const float* __restrict__ lws) {
    size_t idx = (size_t)blockIdx.x * 256 + threadIdx.x;
    int row = (int)(idx >> 9);
    float linv = 1.f / lws[row];
    float4* p = (float4*)w + idx;
    float4 v = *p;
    v.x *= linv; v.y *= linv; v.z *= linv; v.w *= linv;
    *p = v;
}

// ===================== fallback path (round-1, correct at 354us) =====================

__global__ __launch_bounds__(256) void norms_kernel(const float* __restrict__ q,
                                                    const float* __restrict__ k,
                                                    float* __restrict__ ws) {
    int row = blockIdx.x * 4 + (threadIdx.x >> 6);
    int lane = threadIdx.x & 63;
    const int NR = B_ * S_;
    const float* src = (row < NR) ? q : k;
    int r = (row < NR) ? row : row - NR;
    const float* p = src + (size_t)r * D_;
    float x0 = p[lane], x1 = p[lane + 64];
    float a = x0 * x0 + x1 * x1;
#pragma unroll
    for (int m = 1; m <= 32; m <<= 1) a += __shfl_xor(a, m, 64);
    if (lane == 0) ws[row] = a;
}

__global__ __launch_bounds__(256) void attn_kernel(
    const float* __restrict__ qg, const float* __restrict__ kg, const float* __restrict__ vg,
    const float* __restrict__ cp, const float* __restrict__ betap, const float* __restrict__ biasp,
    const float* __restrict__ ws, float* __restrict__ lws,
    float* __restrict__ houtg, float* __restrict__ woutg) {

    __shared__ float Qs[32][D_ + 4];
    __shared__ float KsT[D_][64 + 4];
    __shared__ float Vs[64][D_];
    __shared__ float Ps[32][64 + 4];
    __shared__ float qn_s[32];
    __shared__ float kn_s[64];
    __shared__ float l_row[32];

    const int tid = threadIdx.x;
    int xcd = blockIdx.x & 7;
    int b = xcd >> 1;
    int rb = (blockIdx.x >> 3) * 2 + (xcd & 1);
    int s0 = rb * 32;

    const float cc = cp[0];
    const float beta = betap[0];
    const float bias = biasp[0];
    const float beta_pos = fmaxf(beta, 0.f) + log1pf(__expf(-fabsf(beta)));
    const float sqrt_c = sqrtf(cc);
    const float inv_sqrt_c = 1.f / sqrt_c;

    const float* qn = ws;
    const float* kn = ws + B_ * S_;
    const size_t bS = (size_t)b * S_;

    {
        int d4 = tid & 31, rr0 = tid >> 5;
#pragma unroll
        for (int it = 0; it < 4; ++it) {
            int rr = it * 8 + rr0;
            float4 v = *(const float4*)(qg + (bS + s0 + rr) * D_ + d4 * 4);
            *(float4*)&Qs[rr][d4 * 4] = v;
        }
    }
    if (tid < 32) { qn_s[tid] = qn[bS + s0 + tid]; l_row[tid] = 0.f; }

    const int cg = tid & 15, rg = tid >> 4;
    const int c0 = cg * 4, r0 = rg * 2;
    const int cgv = tid & 31, rgv = tid >> 5;
    const int c0v = cgv * 4, r0v = rgv * 4;

    float o[4][4];
#pragma unroll
    for (int i = 0; i < 4; ++i)
#pragma unroll
        for (int j = 0; j < 4; ++j) o[i][j] = 0.f;

    for (int t0 = 0; t0 < S_; t0 += 64) {
        __syncthreads();
        {
            int d = tid & 127, seg = tid >> 7;
#pragma unroll
            for (int it = 0; it < 8; ++it) {
                int cbase = it * 8 + seg * 4;
                float f0 = kg[(bS + t0 + cbase + 0) * D_ + d];
                float f1 = kg[(bS + t0 + cbase + 1) * D_ + d];
                float f2 = kg[(bS + t0 + cbase + 2) * D_ + d];
                float f3 = kg[(bS + t0 + cbase + 3) * D_ + d];
                float4 w = {f0, f1, f2, f3};
                *(float4*)&KsT[d][cbase] = w;
            }
        }
        {
            int d4 = tid & 31, rv = tid >> 5;
#pragma unroll
            for (int it = 0; it < 8; ++it) {
                int rr = it * 8 + rv;
                *(float4*)&Vs[rr][d4 * 4] = *(const float4*)(vg + (bS + t0 + rr) * D_ + d4 * 4);
            }
        }
        if (tid < 64) kn_s[tid] = kn[bS + t0 + tid];
        __syncthreads();

        float acc[2][4];
#pragma unroll
        for (int i = 0; i < 2; ++i)
#pragma unroll
            for (int j = 0; j < 4; ++j) acc[i][j] = 0.f;

#pragma unroll 4
        for (int d = 0; d < D_; ++d) {
            float4 kv = *(const float4*)&KsT[d][c0];
            float q0 = Qs[r0][d];
            float q1 = Qs[r0 + 1][d];
            acc[0][0] = fmaf(q0, kv.x, acc[0][0]);
            acc[0][1] = fmaf(q0, kv.y, acc[0][1]);
            acc[0][2] = fmaf(q0, kv.z, acc[0][2]);
            acc[0][3] = fmaf(q0, kv.w, acc[0][3]);
            acc[1][0] = fmaf(q1, kv.x, acc[1][0]);
            acc[1][1] = fmaf(q1, kv.y, acc[1][1]);
            acc[1][2] = fmaf(q1, kv.z, acc[1][2]);
            acc[1][3] = fmaf(q1, kv.w, acc[1][3]);
        }

        float lp[2] = {0.f, 0.f};
#pragma unroll
        for (int i = 0; i < 2; ++i) {
            int r = r0 + i;
            float xn = qn_s[r];
            float one_m_cxn = 1.f - cc * xn;
            float4 pv;
            float* pp = &pv.x;
#pragma unroll
            for (int j = 0; j < 4; ++j) {
                float yn = kn_s[c0 + j];
                float diff = xn - 2.f * acc[i][j] + yn;
                float den = one_m_cxn * (1.f - cc * yn);
                den = fmaxf(den, EPSF);
                float arg = 1.f + 2.f * cc * diff / den;
                arg = fmaxf(arg, 1.f + EPSF);
                float dist = __logf(arg + sqrtf(arg * arg - 1.f)) * inv_sqrt_c;
                float p = __expf(fmaf(-beta_pos, dist, -bias));
                pp[j] = p;
                lp[i] += p;
            }
            *(float4*)&Ps[r][c0] = pv;
            *(float4*)(woutg + (bS + s0 + r) * S_ + t0 + c0) = pv;
        }
#pragma unroll
        for (int m = 1; m <= 8; m <<= 1) {
            lp[0] += __shfl_xor(lp[0], m, 64);
            lp[1] += __shfl_xor(lp[1], m, 64);
        }
        if (cg == 0) { l_row[r0] += lp[0]; l_row[r0 + 1] += lp[1]; }
        __syncthreads();

#pragma unroll 4
        for (int kk = 0; kk < 64; ++kk) {
            float4 vv = *(const float4*)&Vs[kk][c0v];
            float pa0 = Ps[r0v + 0][kk];
            float pa1 = Ps[r0v + 1][kk];
            float pa2 = Ps[r0v + 2][kk];
            float pa3 = Ps[r0v + 3][kk];
            o[0][0] = fmaf(pa0, vv.x, o[0][0]);
            o[0][1] = fmaf(pa0, vv.y, o[0][1]);
            o[0][2] = fmaf(pa0, vv.z, o[0][2]);
            o[0][3] = fmaf(pa0, vv.w, o[0][3]);
            o[1][0] = fmaf(pa1, vv.x, o[1][0]);
            o[1][1] = fmaf(pa1, vv.y, o[1][1]);
            o[1][2] = fmaf(pa1, vv.z, o[1][2]);
            o[1][3] = fmaf(pa1, vv.w, o[1][3]);
            o[2][0] = fmaf(pa2, vv.x, o[2][0]);
            o[2][1] = fmaf(pa2, vv.y, o[2][1]);
            o[2][2] = fmaf(pa2, vv.z, o[2][2]);
            o[2][3] = fmaf(pa2, vv.w, o[2][3]);
            o[3][0] = fmaf(pa3, vv.x, o[3][0]);
            o[3][1] = fmaf(pa3, vv.y, o[3][1]);
            o[3][2] = fmaf(pa3, vv.z, o[3][2]);
            o[3][3] = fmaf(pa3, vv.w, o[3][3]);
        }
    }
    __syncthreads();

#pragma unroll
    for (int i = 0; i < 4; ++i) {
        int r = r0v + i;
        float l = l_row[r];
        float linv = 1.f / l;
        float x0 = o[i][0] * linv;
        float x1 = o[i][1] * linv;
        float x2 = o[i][2] * linv;
        float x3 = o[i][3] * linv;
        float nsq = x0 * x0 + x1 * x1 + x2 * x2 + x3 * x3;
#pragma unroll
        for (int m = 1; m <= 16; m <<= 1) nsq += __shfl_xor(nsq, m, 64);
        float vn = fmaxf(sqrtf(nsq), EPSF);
        float sc = tanhf(sqrt_c * vn) * inv_sqrt_c / vn;
        float4 outv = {x0 * sc, x1 * sc, x2 * sc, x3 * sc};
        *(float4*)(houtg + (bS + s0 + r) * D_ + c0v) = outv;
        if (cgv == 0) lws[bS + s0 + r] = l;
    }
}

// ===================== launch =====================

extern "C" void kernel_launch(void* const* d_in, const int* in_sizes, int n_in,
                              void* d_out, int out_size, void* d_ws, size_t ws_size,
                              hipStream_t stream) {
    const float* q    = (const float*)d_in[0];
    const float* k    = (const float*)d_in[1];
    const float* v    = (const float*)d_in[2];
    const float* c    = (const float*)d_in[3];
    const float* beta = (const float*)d_in[4];
    const float* ab   = (const float*)d_in[5];

    float* out  = (float*)d_out;
    float* hout = out;                          // (B,S,D)
    float* wout = out + (size_t)B_ * S_ * D_;   // (B,S,S)

    float* qn  = (float*)d_ws;
    float* kn  = qn + B_ * S_;
    float* lws = kn + B_ * S_;
    char*  wsb = (char*)d_ws;
    const size_t QB_OFF = 98304;
    const size_t KB_OFF = QB_OFF + 2097152;
    const size_t VT_OFF = KB_OFF + 2097152;
    const size_t NEED   = VT_OFF + 2097152;

    if (ws_size >= NEED) {
        unsigned* Qb = (unsigned*)(wsb + QB_OFF);
        unsigned* Kb = (unsigned*)(wsb + KB_OFF);
        uint4*   Vtb = (uint4*)(wsb + VT_OFF);
        convqk_kernel<<<4096, 256, 0, stream>>>(q, k, qn, kn, Qb, Kb);
        convv_kernel<<<64, 256, 0, stream>>>(v, Vtb);
        hattn_kernel<<<256, 512, 0, stream>>>((const unsigned short*)Qb, (const char*)Kb,
                                              (const char*)Vtb, qn, kn, c, beta, ab,
                                              lws, hout, wout);
        wnorm_kernel<<<(B_ * S_ * S_ / 4) / 256, 256, 0, stream>>>(wout, lws);
    } else {
        norms_kernel<<<(2 * B_ * S_) / 4, 256, 0, stream>>>(q, k, qn);
        attn_kernel<<<(B_ * S_) / 32, 256, 0, stream>>>(q, k, v, c, beta, ab, qn, lws, hout, wout);
        wnorm_kernel<<<(B_ * S_ * S_ / 4) / 256, 256, 0, stream>>>(wout, lws);
    }
}

// Round 3
// 147.493 us; speedup vs baseline: 2.3999x; 1.1301x over previous
//
#include <hip/hip_runtime.h>
#include <math.h>

#define B_ 4
#define S_ 2048
#define D_ 128
#define EPSF 1e-5f
#define BN 128
#define PSB 272   // Ps row stride in bytes (136 bf16): 16B-aligned rows

typedef __attribute__((ext_vector_type(8))) short short8;
typedef __attribute__((ext_vector_type(4))) float f32x4;

static __device__ __forceinline__ unsigned short f2bf(float f) {
    unsigned u = __float_as_uint(f);
    return (unsigned short)((u + 0x7fffu + ((u >> 16) & 1u)) >> 16);
}

static __device__ __forceinline__ void gload_lds16(const void* g, void* l) {
    __builtin_amdgcn_global_load_lds((const __attribute__((address_space(1))) unsigned*)g,
                                     (__attribute__((address_space(3))) unsigned*)l, 16, 0, 0);
}

// ===================== pre-pass kernels (shared by both paths) =====================
// ws bytes: [0,32K) qn, [32K,64K) kn, [64K,96K) lws, [96K..) Qb(2M) Kb(2M) Vtb(2M) [Opart(8M) Pws(33.5M)]

__global__ __launch_bounds__(256) void convqk_kernel(const float* __restrict__ q,
                                                     const float* __restrict__ k,
                                                     float* __restrict__ qn, float* __restrict__ kn,
                                                     float* __restrict__ lws,
                                                     unsigned* __restrict__ Qb, unsigned* __restrict__ Kb) {
    int row = blockIdx.x * 4 + (threadIdx.x >> 6);   // one wave per row, 16384 rows
    int lane = threadIdx.x & 63;
    const int NR = B_ * S_;
    bool isQ = row < NR;
    int r = isQ ? row : row - NR;
    float2 v = ((const float2*)(isQ ? q : k))[(size_t)r * 64 + lane];
    unsigned pk = (unsigned)f2bf(v.x) | ((unsigned)f2bf(v.y) << 16);
    float nrm = v.x * v.x + v.y * v.y;
#pragma unroll
    for (int m = 1; m <= 32; m <<= 1) nrm += __shfl_xor(nrm, m, 64);
    if (isQ) {
        Qb[(size_t)r * 64 + lane] = pk;              // plain row-major
        if (lane == 0) qn[r] = nrm;
        if (lane == 1) lws[r] = 0.f;                 // zero l accumulator for hattn2 atomics
    } else {
        int c = lane >> 2;                           // 16B chunk index 0..15
        int cs = c ^ (r & 7);                        // bake LDS bank swizzle into global layout
        Kb[(size_t)r * 64 + cs * 4 + (lane & 3)] = pk;
        if (lane == 0) kn[r] = nrm;
    }
}

__global__ __launch_bounds__(256) void convv_kernel(const float* __restrict__ v, uint4* __restrict__ Vtb) {
    __shared__ unsigned short Vs[128 * 132];
    int b = blockIdx.x >> 4;
    int t = blockIdx.x & 15;
    int tid = threadIdx.x;
    const float* src = v + ((size_t)b * S_ + t * 128) * D_;
    int d4 = tid & 31, key0 = tid >> 5;
#pragma unroll
    for (int it = 0; it < 16; ++it) {
        int key = key0 + it * 8;
        float4 f = *(const float4*)(src + (size_t)key * D_ + d4 * 4);
        unsigned short* dst = &Vs[key * 132 + d4 * 4];
        dst[0] = f2bf(f.x); dst[1] = f2bf(f.y); dst[2] = f2bf(f.z); dst[3] = f2bf(f.w);
    }
    __syncthreads();
    uint4* tile = Vtb + (size_t)blockIdx.x * (128 * 16);   // [tile][d=128][16 x 16B chunks]
    int d = tid & 127;
    int cl = tid >> 7;
#pragma unroll
    for (int it = 0; it < 8; ++it) {
        int c = cl + it * 2;
        int kb = c * 8;
        unsigned short e0 = Vs[(kb + 0) * 132 + d], e1 = Vs[(kb + 1) * 132 + d];
        unsigned short e2 = Vs[(kb + 2) * 132 + d], e3 = Vs[(kb + 3) * 132 + d];
        unsigned short e4 = Vs[(kb + 4) * 132 + d], e5 = Vs[(kb + 5) * 132 + d];
        unsigned short e6 = Vs[(kb + 6) * 132 + d], e7 = Vs[(kb + 7) * 132 + d];
        uint4 o;
        o.x = (unsigned)e0 | ((unsigned)e1 << 16);
        o.y = (unsigned)e2 | ((unsigned)e3 << 16);
        o.z = (unsigned)e4 | ((unsigned)e5 << 16);
        o.w = (unsigned)e6 | ((unsigned)e7 << 16);
        tile[d * 16 + (c ^ (d & 7))] = o;
    }
}

// ===================== v2: split-t fused MFMA attention, 2 blocks/CU =====================

__global__ __launch_bounds__(512, 2) void hattn2_kernel(
    const unsigned short* __restrict__ Qb, const char* __restrict__ Kb, const char* __restrict__ Vtb,
    const float* __restrict__ qn, const float* __restrict__ kn,
    const float* __restrict__ cp, const float* __restrict__ betap, const float* __restrict__ biasp,
    float* __restrict__ lws, float* __restrict__ Opart, uint4* __restrict__ Pws) {

    __shared__ __align__(1024) char smem[76032];
    char* KsB = smem;                                // 32 KB: 128 key-rows x 256B (swizzled)
    char* VtB = smem + 32768;                        // 32 KB: 128 d-rows x 256B (swizzled)
    char* PsB = smem + 65536;                        // 8704 B: 32 rows x 272B
    float* yn_s  = (float*)(smem + 74240);           // 512B
    float* gy_s  = (float*)(smem + 74752);           // 512B
    float* xn_s  = (float*)(smem + 75264);           // 128B
    float* rx_s  = (float*)(smem + 75392);           // 128B
    float* l_row = (float*)(smem + 75520);           // 128B

    const int tid = threadIdx.x;
    const int lane = tid & 63, wave = tid >> 6;
    const int wm = wave & 1, wn = wave >> 1;         // wm: 16-row half; wn: 32-col / 32-d slice
    const int lm = lane & 15, quad = lane >> 4;

    const int th = blockIdx.x & 1;                   // t-half
    const int b = (blockIdx.x >> 1) & 3;
    const int rb = blockIdx.x >> 3;                  // 0..63
    const int s0 = rb * 32;
    const size_t bS = (size_t)b * S_;

    const float cc = cp[0], beta = betap[0], bias = biasp[0];
    const float beta_pos = fmaxf(beta, 0.f) + log1pf(__expf(-fabsf(beta)));
    const float sqrt_c = sqrtf(cc);
    const float bneg = -beta_pos / sqrt_c;                 // p = 2^(bneg*log2(w) + bias2)
    const float bias2 = -bias * 1.442695040888963f;
    const float onepe = 1.f + EPSF;
    const float c2 = 2.f * cc;

    if (tid < 32) {
        float xn = qn[bS + s0 + tid];
        xn_s[tid] = xn;
        rx_s[tid] = c2 * __builtin_amdgcn_rcpf(1.f - cc * xn);
        l_row[tid] = 0.f;
    }

    // Q A-frags in registers (A: m=lane&15, k=quad*8+j)
    short8 aq[4];
    {
        const unsigned short* qrow = Qb + (bS + s0 + wm * 16 + lm) * D_;
#pragma unroll
        for (int ks = 0; ks < 4; ++ks)
            aq[ks] = *(const short8*)(qrow + ks * 32 + quad * 8);
    }

    f32x4 o0 = {0.f, 0.f, 0.f, 0.f}, o1 = {0.f, 0.f, 0.f, 0.f};

    const char* KbBase = Kb + bS * 256;
    const char* VtBase = Vtb + (size_t)b * 16 * 32768;

    for (int it = 0; it < 8; ++it) {
        int t = th * 8 + it;
        int t0 = t * BN;
        __syncthreads();
        // async stage K chunk + Vt tile (verbatim 32KB linear copies, pre-swizzled)
        {
            const char* ks = KbBase + (size_t)t0 * 256;
            const char* vs = VtBase + (size_t)t * 32768;
#pragma unroll
            for (int j = 0; j < 4; ++j) {
                int off = (tid + j * 512) * 16;
                gload_lds16(ks + off, KsB + off);
                gload_lds16(vs + off, VtB + off);
            }
            if (tid < BN) {
                float yn = kn[bS + t0 + tid];
                yn_s[tid] = yn;
                gy_s[tid] = __builtin_amdgcn_rcpf(1.f - cc * yn);
            }
        }
        __syncthreads();

        // ---- S = Q K^T (wave tile 16x32) ----
        f32x4 acc0 = {0.f, 0.f, 0.f, 0.f}, acc1 = {0.f, 0.f, 0.f, 0.f};
#pragma unroll
        for (int ks = 0; ks < 4; ++ks) {
            int n0 = wn * 32 + lm;
            int c = ks * 4 + quad;
            short8 b0 = *(const short8*)(KsB + n0 * 256 + ((c ^ (n0 & 7)) * 16));
            int n1 = n0 + 16;
            short8 b1 = *(const short8*)(KsB + n1 * 256 + ((c ^ (n1 & 7)) * 16));
            acc0 = __builtin_amdgcn_mfma_f32_16x16x32_bf16(aq[ks], b0, acc0, 0, 0, 0);
            acc1 = __builtin_amdgcn_mfma_f32_16x16x32_bf16(aq[ks], b1, acc1, 0, 0, 0);
        }

        // ---- dist -> p = exp2(bneg*log2(arg+sqrt(arg^2-1)) + bias2), unnormalized ----
        int col0 = wn * 32 + lm, col1 = col0 + 16;
        float yn0 = yn_s[col0], gy0 = gy_s[col0];
        float yn1 = yn_s[col1], gy1 = gy_s[col1];
#pragma unroll
        for (int r = 0; r < 4; ++r) {
            int row = wm * 16 + quad * 4 + r;        // C/D layout: row=(lane>>4)*4+reg
            float xn = xn_s[row];
            float rx = rx_s[row];

            float diff0 = fmaf(-2.f, acc0[r], xn + yn0);
            float arg0 = fmaf(diff0 * gy0, rx, 1.f);
            arg0 = fmaxf(arg0, onepe);
            float w0 = arg0 + sqrtf(fmaf(arg0, arg0, -1.f));
            float p0 = __builtin_amdgcn_exp2f(fmaf(bneg, __builtin_amdgcn_logf(w0), bias2));

            float diff1 = fmaf(-2.f, acc1[r], xn + yn1);
            float arg1 = fmaf(diff1 * gy1, rx, 1.f);
            arg1 = fmaxf(arg1, onepe);
            float w1 = arg1 + sqrtf(fmaf(arg1, arg1, -1.f));
            float p1 = __builtin_amdgcn_exp2f(fmaf(bneg, __builtin_amdgcn_logf(w1), bias2));

            *(unsigned short*)(PsB + row * PSB + col0 * 2) = f2bf(p0);
            *(unsigned short*)(PsB + row * PSB + col1 * 2) = f2bf(p1);

            float s = p0 + p1;
#pragma unroll
            for (int m = 1; m <= 8; m <<= 1) s += __shfl_xor(s, m, 64);
            if (lm == 0) atomicAdd(&l_row[row], s);
        }
        __syncthreads();

        // ---- coalesced P tile -> global bf16 (32x128 = 8KB = 512 x uint4) ----
        {
            int row = tid >> 4, chunk = tid & 15;
            uint4 pv = *(const uint4*)(PsB + row * PSB + chunk * 16);
            Pws[(((bS + s0 + row) * S_ + t0) >> 3) + chunk] = pv;
        }

        // ---- O += P V (wave tile 16 rows x 32 d) ----
#pragma unroll
        for (int ks = 0; ks < 4; ++ks) {
            short8 ap = *(const short8*)(PsB + (wm * 16 + lm) * PSB + (ks * 32 + quad * 8) * 2);
            int d0 = wn * 32 + lm;
            int c = ks * 4 + quad;
            short8 v0 = *(const short8*)(VtB + d0 * 256 + ((c ^ (d0 & 7)) * 16));
            int d1 = d0 + 16;
            short8 v1 = *(const short8*)(VtB + d1 * 256 + ((c ^ (d1 & 7)) * 16));
            o0 = __builtin_amdgcn_mfma_f32_16x16x32_bf16(ap, v0, o0, 0, 0, 0);
            o1 = __builtin_amdgcn_mfma_f32_16x16x32_bf16(ap, v1, o1, 0, 0, 0);
        }
    }
    __syncthreads();

    // ---- write partial O (unnormalized) + accumulate l globally ----
    float* op = Opart + (size_t)th * (B_ * S_ * D_) + (bS + s0) * D_;
#pragma unroll
    for (int r = 0; r < 4; ++r) {
        int row = wm * 16 + quad * 4 + r;
        op[(size_t)row * D_ + wn * 32 + lm] = o0[r];
        op[(size_t)row * D_ + wn * 32 + 16 + lm] = o1[r];
    }
    if (tid < 32) atomicAdd(&lws[bS + s0 + tid], l_row[tid]);
}

// combine partial O, normalize, exp-map
__global__ __launch_bounds__(256) void hepi_kernel(const float* __restrict__ Opart,
                                                   const float* __restrict__ lws,
                                                   const float* __restrict__ cp,
                                                   float* __restrict__ hout) {
    int row = blockIdx.x * 4 + (threadIdx.x >> 6);   // one wave per row
    int lane = threadIdx.x & 63;
    const float cc = cp[0];
    const float sqrt_c = sqrtf(cc);
    float2 a = ((const float2*)(Opart + (size_t)row * D_))[lane];
    float2 b = ((const float2*)(Opart + (size_t)(B_ * S_ * D_) + (size_t)row * D_))[lane];
    float linv = 1.f / lws[row];
    float x0 = (a.x + b.x) * linv;
    float x1 = (a.y + b.y) * linv;
    float np = x0 * x0 + x1 * x1;
#pragma unroll
    for (int m = 1; m <= 32; m <<= 1) np += __shfl_xor(np, m, 64);
    float vn = fmaxf(sqrtf(np), EPSF);
    float aa = sqrt_c * vn;
    float t = 1.f - 2.f / (__expf(2.f * aa) + 1.f);  // tanh(aa)
    float sc = t / aa;                                // tanh(sqrt_c*vn)/sqrt_c/vn
    float2 o = {x0 * sc, x1 * sc};
    ((float2*)(hout + (size_t)row * D_))[lane] = o;
}

// expand bf16 P -> normalized fp32 W
__global__ __launch_bounds__(256) void wnorm2_kernel(const uint4* __restrict__ Pws,
                                                     const float* __restrict__ lws,
                                                     float* __restrict__ w) {
    size_t idx = (size_t)blockIdx.x * 256 + threadIdx.x;   // uint4 index (8 bf16)
    int row = (int)(idx >> 8);                             // 256 uint4 per 2048-col row
    float linv = 1.f / lws[row];
    uint4 u = Pws[idx];
    float4 f0, f1;
    f0.x = __uint_as_float(u.x << 16) * linv;
    f0.y = __uint_as_float(u.x & 0xffff0000u) * linv;
    f0.z = __uint_as_float(u.y << 16) * linv;
    f0.w = __uint_as_float(u.y & 0xffff0000u) * linv;
    f1.x = __uint_as_float(u.z << 16) * linv;
    f1.y = __uint_as_float(u.z & 0xffff0000u) * linv;
    f1.z = __uint_as_float(u.w << 16) * linv;
    f1.w = __uint_as_float(u.w & 0xffff0000u) * linv;
    float4* out = (float4*)w + idx * 2;
    out[0] = f0;
    out[1] = f1;
}

// ===================== round-2 path (proven, ws fallback) =====================

__global__ __launch_bounds__(512, 2) void hattn_kernel(
    const unsigned short* __restrict__ Qb, const char* __restrict__ Kb, const char* __restrict__ Vtb,
    const float* __restrict__ qn, const float* __restrict__ kn,
    const float* __restrict__ cp, const float* __restrict__ betap, const float* __restrict__ biasp,
    float* __restrict__ lws, float* __restrict__ houtg, float* __restrict__ woutg) {

    __shared__ __align__(1024) char smem[75136];
    char* KsB = smem;
    char* VtB = smem + 32768;
    char* PsB = smem + 65536;
    float* kn_s  = (float*)(smem + 74240);
    float* qn_s  = (float*)(smem + 74752);
    float* l_row = (float*)(smem + 74880);
    float* nsq_s = (float*)(smem + 75008);

    const int tid = threadIdx.x;
    const int lane = tid & 63, wave = tid >> 6;
    const int wm = wave & 1, wn = wave >> 1;
    const int lm = lane & 15, quad = lane >> 4;

    int xcd = blockIdx.x & 7;
    int b = xcd >> 1;
    int rb = (blockIdx.x >> 3) * 2 + (xcd & 1);
    int s0 = rb * 32;
    const size_t bS = (size_t)b * S_;

    const float cc = cp[0], beta = betap[0], bias = biasp[0];
    const float beta_pos = fmaxf(beta, 0.f) + log1pf(__expf(-fabsf(beta)));
    const float sqrt_c = sqrtf(cc);
    const float inv_sqrt_c = 1.f / sqrt_c;

    if (tid < 32) {
        qn_s[tid] = qn[bS + s0 + tid];
        l_row[tid] = 0.f;
        nsq_s[tid] = 0.f;
    }

    short8 aq[4];
    {
        const unsigned short* qrow = Qb + (bS + s0 + wm * 16 + lm) * D_;
#pragma unroll
        for (int ks = 0; ks < 4; ++ks)
            aq[ks] = *(const short8*)(qrow + ks * 32 + quad * 8);
    }

    f32x4 o0 = {0.f, 0.f, 0.f, 0.f}, o1 = {0.f, 0.f, 0.f, 0.f};

    const char* KbBase = Kb + bS * 256;
    const char* VtBase = Vtb + (size_t)b * 16 * 32768;

    for (int t = 0; t < S_ / BN; ++t) {
        int t0 = t * BN;
        __syncthreads();
        {
            const uint4* ksrc = (const uint4*)(KbBase + (size_t)t0 * 256);
            const uint4* vsrc = (const uint4*)(VtBase + (size_t)t * 32768);
            uint4* kd = (uint4*)KsB;
            uint4* vd = (uint4*)VtB;
#pragma unroll
            for (int i = 0; i < 4; ++i) {
                kd[tid + i * 512] = ksrc[tid + i * 512];
                vd[tid + i * 512] = vsrc[tid + i * 512];
            }
            if (tid < BN) kn_s[tid] = kn[bS + t0 + tid];
        }
        __syncthreads();

        f32x4 acc0 = {0.f, 0.f, 0.f, 0.f}, acc1 = {0.f, 0.f, 0.f, 0.f};
#pragma unroll
        for (int ks = 0; ks < 4; ++ks) {
            int n0 = wn * 32 + lm;
            int c = ks * 4 + quad;
            short8 b0 = *(const short8*)(KsB + n0 * 256 + ((c ^ (n0 & 7)) * 16));
            int n1 = n0 + 16;
            short8 b1 = *(const short8*)(KsB + n1 * 256 + ((c ^ (n1 & 7)) * 16));
            acc0 = __builtin_amdgcn_mfma_f32_16x16x32_bf16(aq[ks], b0, acc0, 0, 0, 0);
            acc1 = __builtin_amdgcn_mfma_f32_16x16x32_bf16(aq[ks], b1, acc1, 0, 0, 0);
        }

        float lp[4];
#pragma unroll
        for (int r = 0; r < 4; ++r) {
            int row = wm * 16 + quad * 4 + r;
            float xn = qn_s[row];
            float fx = 1.f - cc * xn;
            float p0, p1;
#pragma unroll
            for (int nt = 0; nt < 2; ++nt) {
                int col = wn * 32 + nt * 16 + lm;
                float dot = (nt == 0) ? acc0[r] : acc1[r];
                float yn = kn_s[col];
                float diff = xn - 2.f * dot + yn;
                float den = fmaxf(fx * (1.f - cc * yn), EPSF);
                float arg = fmaf(2.f * cc * diff, __builtin_amdgcn_rcpf(den), 1.f);
                arg = fmaxf(arg, 1.f + EPSF);
                float dist = __logf(arg + sqrtf(arg * arg - 1.f)) * inv_sqrt_c;
                float p = __expf(fmaf(-beta_pos, dist, -bias));
                woutg[(bS + s0 + row) * S_ + t0 + col] = p;
                *(unsigned short*)(PsB + row * PSB + col * 2) = f2bf(p);
                if (nt == 0) p0 = p; else p1 = p;
            }
            lp[r] = p0 + p1;
        }
#pragma unroll
        for (int r = 0; r < 4; ++r) {
            float s = lp[r];
#pragma unroll
            for (int m = 1; m <= 8; m <<= 1) s += __shfl_xor(s, m, 64);
            if (lm == 0) atomicAdd(&l_row[wm * 16 + quad * 4 + r], s);
        }
        __syncthreads();

#pragma unroll
        for (int ks = 0; ks < 4; ++ks) {
            short8 ap = *(const short8*)(PsB + (wm * 16 + lm) * PSB + (ks * 32 + quad * 8) * 2);
            int d0 = wn * 32 + lm;
            int c = ks * 4 + quad;
            short8 v0 = *(const short8*)(VtB + d0 * 256 + ((c ^ (d0 & 7)) * 16));
            int d1 = d0 + 16;
            short8 v1 = *(const short8*)(VtB + d1 * 256 + ((c ^ (d1 & 7)) * 16));
            o0 = __builtin_amdgcn_mfma_f32_16x16x32_bf16(ap, v0, o0, 0, 0, 0);
            o1 = __builtin_amdgcn_mfma_f32_16x16x32_bf16(ap, v1, o1, 0, 0, 0);
        }
    }
    __syncthreads();

    float xs0[4], xs1[4];
#pragma unroll
    for (int r = 0; r < 4; ++r) {
        int row = wm * 16 + quad * 4 + r;
        float linv = __builtin_amdgcn_rcpf(l_row[row]);
        float x0 = o0[r] * linv, x1 = o1[r] * linv;
        xs0[r] = x0; xs1[r] = x1;
        float np = x0 * x0 + x1 * x1;
#pragma unroll
        for (int m = 1; m <= 8; m <<= 1) np += __shfl_xor(np, m, 64);
        if (lm == 0) atomicAdd(&nsq_s[row], np);
    }
    if (tid < 32) lws[bS + s0 + tid] = l_row[tid];
    __syncthreads();
#pragma unroll
    for (int r = 0; r < 4; ++r) {
        int row = wm * 16 + quad * 4 + r;
        float vn = fmaxf(sqrtf(nsq_s[row]), EPSF);
        float a = sqrt_c * vn;
        float th = 1.f - 2.f * __builtin_amdgcn_rcpf(__expf(2.f * a) + 1.f);
        float sc = th / a;
        houtg[(bS + s0 + row) * D_ + wn * 32 + lm] = xs0[r] * sc;
        houtg[(bS + s0 + row) * D_ + wn * 32 + 16 + lm] = xs1[r] * sc;
    }
}

__global__ __launch_bounds__(256) void wnorm_kernel(float* __restrict__ w,
                                                    const float* __restrict__ lws) {
    size_t idx = (size_t)blockIdx.x * 256 + threadIdx.x;
    int row = (int)(idx >> 9);
    float linv = 1.f / lws[row];
    float4* p = (float4*)w + idx;
    float4 v = *p;
    v.x *= linv; v.y *= linv; v.z *= linv; v.w *= linv;
    *p = v;
}

// ===================== launch =====================

extern "C" void kernel_launch(void* const* d_in, const int* in_sizes, int n_in,
                              void* d_out, int out_size, void* d_ws, size_t ws_size,
                              hipStream_t stream) {
    const float* q    = (const float*)d_in[0];
    const float* k    = (const float*)d_in[1];
    const float* v    = (const float*)d_in[2];
    const float* c    = (const float*)d_in[3];
    const float* beta = (const float*)d_in[4];
    const float* ab   = (const float*)d_in[5];

    float* out  = (float*)d_out;
    float* hout = out;                          // (B,S,D)
    float* wout = out + (size_t)B_ * S_ * D_;   // (B,S,S)

    float* qn  = (float*)d_ws;
    float* kn  = qn + B_ * S_;
    float* lws = kn + B_ * S_;
    char*  wsb = (char*)d_ws;
    const size_t QB_OFF = 98304;
    const size_t KB_OFF = QB_OFF + 2097152;
    const size_t VT_OFF = KB_OFF + 2097152;
    const size_t NEED1  = VT_OFF + 2097152;
    const size_t OP_OFF = NEED1;
    const size_t PW_OFF = OP_OFF + 2u * B_ * S_ * D_ * 4;           // 8 MB partial O
    const size_t NEED2  = PW_OFF + (size_t)B_ * S_ * S_ * 2;        // 33.5 MB bf16 P

    unsigned* Qb = (unsigned*)(wsb + QB_OFF);
    unsigned* Kb = (unsigned*)(wsb + KB_OFF);
    uint4*   Vtb = (uint4*)(wsb + VT_OFF);

    if (ws_size >= NEED2) {
        float* Opart = (float*)(wsb + OP_OFF);
        uint4* Pws   = (uint4*)(wsb + PW_OFF);
        convqk_kernel<<<4096, 256, 0, stream>>>(q, k, qn, kn, lws, Qb, Kb);
        convv_kernel<<<64, 256, 0, stream>>>(v, Vtb);
        hattn2_kernel<<<512, 512, 0, stream>>>((const unsigned short*)Qb, (const char*)Kb,
                                               (const char*)Vtb, qn, kn, c, beta, ab,
                                               lws, Opart, Pws);
        hepi_kernel<<<2048, 256, 0, stream>>>(Opart, lws, c, hout);
        wnorm2_kernel<<<8192, 256, 0, stream>>>(Pws, lws, wout);
    } else {
        convqk_kernel<<<4096, 256, 0, stream>>>(q, k, qn, kn, lws, Qb, Kb);
        convv_kernel<<<64, 256, 0, stream>>>(v, Vtb);
        hattn_kernel<<<256, 512, 0, stream>>>((const unsigned short*)Qb, (const char*)Kb,
                                              (const char*)Vtb, qn, kn, c, beta, ab,
                                              lws, hout, wout);
        wnorm_kernel<<<(B_ * S_ * S_ / 4) / 256, 256, 0, stream>>>(wout, lws);
    }
}